// Round 6
// baseline (258.761 us; speedup 1.0000x reference)
//
#include <hip/hip_runtime.h>
#include <hip/hip_bf16.h>
#include <math.h>

#define D_MODEL 1024
#define HD 128
#define SEQ 4096

typedef __bf16 bf16x8 __attribute__((ext_vector_type(8)));
typedef float f32x4 __attribute__((ext_vector_type(4)));
typedef unsigned int u32;
typedef u32 u32x4 __attribute__((ext_vector_type(4)));

__device__ __forceinline__ unsigned short f2bf(float f) {
    union { float f; u32 u; } c; c.f = f;
    u32 u = c.u;
    u = (u + 0x7fffu + ((u >> 16) & 1u)) >> 16;
    return (unsigned short)u;
}
__device__ __forceinline__ u32 pk2(float a, float b) {
    __hip_bfloat162 h = __float22bfloat162_rn(make_float2(a, b));
    union { __hip_bfloat162 h; u32 u; } c; c.h = h; return c.u;
}
// async global->LDS, 16B/lane; dest = wave-uniform base + lane*16
__device__ __forceinline__ void dma16(void* lds, const void* g) {
    __builtin_amdgcn_global_load_lds(
        (const __attribute__((address_space(1))) u32*)g,
        (__attribute__((address_space(3))) u32*)lds, 16, 0, 0);
}

// ---------------------------------------------------------------------------
// LDS-transposed W -> Wt[n][k] bf16, n in [0,384). Q slice pre-scaled by
// 1/sqrt(128)*log2(e): scores exit QK^T MFMA in the log2 domain.
__global__ __launch_bounds__(256)
void wt_kernel(const float* __restrict__ Wq, const float* __restrict__ Wk,
               const float* __restrict__ Wv, unsigned short* __restrict__ Wt) {
    __shared__ float wsf[64][129];
    const int t = threadIdx.x;
    const int k0 = blockIdx.x * 64;
    const int mat = blockIdx.y;
    const float* W = (mat == 0) ? Wq : (mat == 1) ? Wk : Wv;
    const float sc = (mat == 0) ? (0.08838834764831845f * 1.4426950408889634f) : 1.0f;
    {
        const int r = t >> 2, c = (t & 3) * 32;
        const float* src = W + (size_t)(k0 + r) * HD + c;
        #pragma unroll
        for (int j = 0; j < 32; j += 4)
            *reinterpret_cast<f32x4*>(&wsf[r][c + j]) = *reinterpret_cast<const f32x4*>(src + j);
    }
    __syncthreads();
    const int n = t >> 1, ks = (t & 1) * 32;
    u32 ow[16];
    #pragma unroll
    for (int j = 0; j < 16; ++j)
        ow[j] = pk2(wsf[ks + 2 * j][n] * sc, wsf[ks + 2 * j + 1][n] * sc);
    unsigned short* dst = Wt + (size_t)(mat * HD + n) * D_MODEL + k0 + ks;
    #pragma unroll
    for (int j = 0; j < 4; ++j)
        *reinterpret_cast<u32x4*>(dst + j * 8) = (u32x4){ow[4*j], ow[4*j+1], ow[4*j+2], ow[4*j+3]};
}

// ---------------------------------------------------------------------------
// QKV projection, m97-style: DMA staging (x as fp32, Wt bf16) into XOR-swizzled
// unpadded LDS, BK=32 double-buffered, ONE barrier per iter (DMA issued right
// after the barrier; per-wave vmcnt drains at the NEXT barrier arrival).
// LDS layouts: X[buf][row r][gran G'] = x[row][ (G'^(r&6))*4f ]   (granule=16B)
//              W2[buf][r][G'] = Wt[nbase + r + 64*(G>>2)][k0+(G&3)*8], G=G'^(r&7)
__global__ __launch_bounds__(256)
void proj_kernel(const float* __restrict__ x, const unsigned short* __restrict__ Wt,
                 unsigned short* __restrict__ Qb, unsigned short* __restrict__ Kb,
                 unsigned short* __restrict__ Vt) {
    __shared__ __align__(1024) char ps[32768];   // x: [0,16K) bufs of 8K; Wt: [16K,32K)
    const int t = threadIdx.x;
    const int w = t >> 6, l = t & 63, li = l & 15, g2 = l >> 4;
    const int nbase = blockIdx.x * 128;
    const int rowbase = blockIdx.y * 64;

    f32x4 acc[8];
    #pragma unroll
    for (int nt = 0; nt < 8; ++nt) acc[nt] = (f32x4){0.f, 0.f, 0.f, 0.f};

    const int lrow = l >> 3;                         // row within an 8-row issue
    const int xg = (l & 7) ^ (lrow & 6);             // x source granule
    const int wgr = (l & 7) ^ lrow;                  // Wt raw granule
    const int wrow_add = (wgr >> 2) << 6;            // +64 rows for upper k-half
    const int wkc = (wgr & 3) * 8;

    auto stage = [&](int k0, int buf) {
        #pragma unroll
        for (int j = 0; j < 2; ++j) {
            int r0 = w * 16 + 8 * j;
            dma16(ps + buf * 8192 + r0 * 128,
                  x + (size_t)(rowbase + r0 + lrow) * D_MODEL + k0 + xg * 4);
            dma16(ps + 16384 + buf * 8192 + r0 * 128,
                  Wt + (size_t)(nbase + r0 + lrow + wrow_add) * D_MODEL + k0 + wkc);
        }
    };

    stage(0, 0);
    for (int it = 0; it < 32; ++it) {
        const int buf = it & 1;
        __syncthreads();
        if (it + 1 < 32) stage((it + 1) * 32, buf ^ 1);
        const char* xb = ps + buf * 8192 + (w * 16 + li) * 128 + (((2 * g2) ^ (li & 6)) * 16);
        f32x4 x0 = *reinterpret_cast<const f32x4*>(xb);
        f32x4 x1 = *reinterpret_cast<const f32x4*>(xb + 16);
        union { u32 d[4]; bf16x8 v; } cva;
        cva.d[0] = pk2(x0[0], x0[1]); cva.d[1] = pk2(x0[2], x0[3]);
        cva.d[2] = pk2(x1[0], x1[1]); cva.d[3] = pk2(x1[2], x1[3]);
        bf16x8 af = cva.v;
        #pragma unroll
        for (int nt = 0; nt < 8; ++nt) {
            bf16x8 bfr = *reinterpret_cast<const bf16x8*>(
                ps + 16384 + buf * 8192 + ((nt & 3) * 16 + li) * 128 +
                ((((nt >> 2) * 4 + g2) ^ (li & 7)) * 16));
            acc[nt] = __builtin_amdgcn_mfma_f32_16x16x32_bf16(af, bfr, acc[nt], 0, 0, 0);
        }
    }

    if (nbase < 256) {
        unsigned short* P = nbase ? Kb : Qb;
        #pragma unroll
        for (int nt = 0; nt < 8; ++nt)
            #pragma unroll
            for (int r = 0; r < 4; ++r) {
                int grow = rowbase + w * 16 + g2 * 4 + r;
                P[(size_t)grow * HD + nt * 16 + li] = f2bf(acc[nt][r]);
            }
    } else {
        int grow0 = rowbase + w * 16 + g2 * 4;
        int b_ = grow0 >> 12, s_ = grow0 & 4095;
        #pragma unroll
        for (int nt = 0; nt < 8; ++nt) {
            ushort4 s4;
            s4.x = f2bf(acc[nt][0]); s4.y = f2bf(acc[nt][1]);
            s4.z = f2bf(acc[nt][2]); s4.w = f2bf(acc[nt][3]);
            *reinterpret_cast<ushort4*>(&Vt[((size_t)b_ * HD + nt * 16 + li) * SEQ + s_]) = s4;
        }
    }
}

// ---------------------------------------------------------------------------
// Flash causal attention: fixed-shift softmax (p = exp2(s-16)), 2x2 wave split,
// 4-way key-range split per 64-row q-group (grid 1024), DMA+swizzle staging.
// LDS (40960 B static, 2 blocks/CU at VGPR<=128):
//   K [0,16K):    K[row 0..63][gran G'] = Kb[j0+row][ (G'^(row&7))*8 ]  (16 gran/row)
//   V [16K,32K):  V[d 0..127][G']      = Vt[d][j0 + (G'^(d&7))*8 ]     (8 gran/row)
//   P [32K,40K):  P[q 0..63][G']       = p[q][ (G'^(q&7))*8 ]          (8 gran/row)
__global__ __launch_bounds__(256, 4)
void attn_kernel(const unsigned short* __restrict__ Qb, const unsigned short* __restrict__ Kb,
                 const unsigned short* __restrict__ Vt, float* __restrict__ outO,
                 unsigned short* __restrict__ Obf, float* __restrict__ Lbuf) {
    __shared__ __align__(1024) char smem[40960];
    const int t = threadIdx.x;
    const int w = t >> 6, l = t & 63, li = l & 15, g2 = l >> 4;
    const int qh = w >> 1, kh = w & 1;
    const int b = blockIdx.x & 3;
    const int u = blockIdx.x >> 2;
    const int g = 63 - (u >> 2);               // q-group, heavy first
    const int c = u & 3;                       // key-range chunk
    const int R = g + 1;
    const int ts = (c * R) >> 2, te = ((c + 1) * R) >> 2;
    const int q0 = g * 64;
    const size_t rowb = (size_t)b * SEQ;
    const int koff = kh * 32;

    const unsigned short* KbB = Kb + rowb * HD;
    const unsigned short* VtB = Vt + (size_t)b * HD * SEQ;
    const int vgran = ((l & 7) ^ (l >> 3)) * 8;

    auto stage = [&](int it) {
        const int j0 = it * 64;
        #pragma unroll
        for (int j = 0; j < 4; ++j) {
            int rK = w * 16 + 4 * j + (l >> 4);
            dma16(smem + (w * 16 + 4 * j) * 256,
                  KbB + (size_t)(j0 + rK) * 128 + (((l & 15) ^ (rK & 7)) * 8));
            int rV = w * 32 + 8 * j + (l >> 3);
            dma16(smem + 16384 + (w * 32 + 8 * j) * 128,
                  VtB + (size_t)rV * SEQ + j0 + vgran);
        }
    };

    bf16x8 qf[2][4];
    #pragma unroll
    for (int qt = 0; qt < 2; ++qt)
        #pragma unroll
        for (int ks = 0; ks < 4; ++ks)
            qf[qt][ks] = *reinterpret_cast<const bf16x8*>(
                Qb + (rowb + q0 + qh * 32 + qt * 16 + li) * HD + ks * 32 + g2 * 8);

    f32x4 acco[2][8];
    #pragma unroll
    for (int qt = 0; qt < 2; ++qt)
        #pragma unroll
        for (int dt = 0; dt < 8; ++dt) acco[qt][dt] = (f32x4){0.f, 0.f, 0.f, 0.f};
    float ls[2][4] = {{0.f,0.f,0.f,0.f},{0.f,0.f,0.f,0.f}};

    const int gV = ((4 * kh + g2) ^ (li & 7)) * 16;   // V and P read granule offset

    if (ts < te) stage(ts);
    for (int it = ts; it < te; ++it) {
        __syncthreads();   // per-wave vmcnt(0) drain here completes ALL waves' DMA

        f32x4 accs[2][2];
        #pragma unroll
        for (int qt = 0; qt < 2; ++qt)
            #pragma unroll
            for (int kt = 0; kt < 2; ++kt) accs[qt][kt] = (f32x4){0.f, 0.f, 0.f, 0.f};
        #pragma unroll
        for (int kt = 0; kt < 2; ++kt) {
            const char* kb = smem + (koff + kt * 16 + li) * 256;
            #pragma unroll
            for (int ks = 0; ks < 4; ++ks) {
                bf16x8 kf = *reinterpret_cast<const bf16x8*>(kb + (((4 * ks + g2) ^ (li & 7)) * 16));
                accs[0][kt] = __builtin_amdgcn_mfma_f32_16x16x32_bf16(qf[0][ks], kf, accs[0][kt], 0, 0, 0);
                accs[1][kt] = __builtin_amdgcn_mfma_f32_16x16x32_bf16(qf[1][ks], kf, accs[1][kt], 0, 0, 0);
            }
        }

        const bool masked = (it == g);
        #pragma unroll
        for (int qt = 0; qt < 2; ++qt)
            #pragma unroll
            for (int kt = 0; kt < 2; ++kt)
                #pragma unroll
                for (int r = 0; r < 4; ++r) {
                    float s = accs[qt][kt][r];
                    if (masked && (koff + kt * 16 + li > qh * 32 + qt * 16 + g2 * 4 + r))
                        s = -INFINITY;
                    float p = __builtin_amdgcn_exp2f(s - 16.0f);
                    ls[qt][r] += p;
                    int prow = qh * 32 + qt * 16 + g2 * 4 + r;
                    int gw = (4 * kh + 2 * kt + (li >> 3)) ^ ((4 * g2 + r) & 7);
                    *reinterpret_cast<unsigned short*>(
                        smem + 32768 + prow * 128 + gw * 16 + (li & 7) * 2) = f2bf(p);
                }

        bf16x8 pf0 = *reinterpret_cast<const bf16x8*>(smem + 32768 + (qh * 32 + li) * 128 + gV);
        bf16x8 pf1 = *reinterpret_cast<const bf16x8*>(smem + 32768 + (qh * 32 + 16 + li) * 128 + gV);
        #pragma unroll
        for (int dt = 0; dt < 8; ++dt) {
            bf16x8 vf = *reinterpret_cast<const bf16x8*>(smem + 16384 + (dt * 16 + li) * 128 + gV);
            acco[0][dt] = __builtin_amdgcn_mfma_f32_16x16x32_bf16(pf0, vf, acco[0][dt], 0, 0, 0);
            acco[1][dt] = __builtin_amdgcn_mfma_f32_16x16x32_bf16(pf1, vf, acco[1][dt], 0, 0, 0);
        }
        __syncthreads();   // all reads of K/V/P done before restaging
        if (it + 1 < te) stage(it + 1);
    }

    // per-lane l -> per-row l (16 key-lanes)
    #pragma unroll
    for (int d = 1; d < 16; d <<= 1)
        #pragma unroll
        for (int qt = 0; qt < 2; ++qt)
            #pragma unroll
            for (int r = 0; r < 4; ++r)
                ls[qt][r] += __shfl_xor(ls[qt][r], d);

    // combine kh halves via LDS overlay (stage buffers dead now)
    float (*Osum)[132] = (float(*)[132])smem;        // 64 x 128 (+4 pad) f32
    float* Lsh = (float*)(smem + 33792);             // [2][64]
    __syncthreads();
    if (kh == 0) {
        #pragma unroll
        for (int qt = 0; qt < 2; ++qt) {
            #pragma unroll
            for (int dt = 0; dt < 8; ++dt)
                #pragma unroll
                for (int r = 0; r < 4; ++r)
                    Osum[qh * 32 + qt * 16 + g2 * 4 + r][dt * 16 + li] = acco[qt][dt][r];
            if (li == 0)
                #pragma unroll
                for (int r = 0; r < 4; ++r)
                    Lsh[qh * 32 + qt * 16 + g2 * 4 + r] = ls[qt][r];
        }
    }
    __syncthreads();
    if (kh == 1) {
        #pragma unroll
        for (int qt = 0; qt < 2; ++qt) {
            #pragma unroll
            for (int dt = 0; dt < 8; ++dt)
                #pragma unroll
                for (int r = 0; r < 4; ++r)
                    Osum[qh * 32 + qt * 16 + g2 * 4 + r][dt * 16 + li] += acco[qt][dt][r];
            if (li == 0)
                #pragma unroll
                for (int r = 0; r < 4; ++r)
                    Lsh[64 + qh * 32 + qt * 16 + g2 * 4 + r] = ls[qt][r];
        }
    }
    __syncthreads();

    if (t < 64)
        Lbuf[(size_t)c * 16384 + rowb + q0 + t] = Lsh[t] + Lsh[64 + t];
    #pragma unroll
    for (int k = 0; k < 8; ++k) {
        int idx = t + k * 256;
        int row = idx >> 5, col = (idx & 31) * 4;
        f32x4 o = *reinterpret_cast<const f32x4*>(&Osum[row][col]);
        size_t grow = rowb + q0 + row;
        if (c == 3) {
            *reinterpret_cast<f32x4*>(&outO[grow * HD + col]) = o;
        } else {
            union { u32 d[2]; uint2 v; } pkd;
            pkd.d[0] = pk2(o[0], o[1]); pkd.d[1] = pk2(o[2], o[3]);
            *reinterpret_cast<uint2*>(&Obf[(size_t)c * 2097152 + grow * HD + col]) = pkd.v;
        }
    }
}

// ---------------------------------------------------------------------------
// Merge: out = (Obf[0]+Obf[1]+Obf[2]+out) / (l0+l1+l2+l3)
__global__ __launch_bounds__(256)
void merge_kernel(float* __restrict__ outO, const unsigned short* __restrict__ Obf,
                  const float* __restrict__ Lbuf) {
    int tid = blockIdx.x * 256 + threadIdx.x;
    #pragma unroll
    for (int k = 0; k < 4; ++k) {
        int idx = tid + k * 131072;
        int row = idx >> 5, col = (idx & 31) * 4;
        float lsum = Lbuf[row] + Lbuf[16384 + row] + Lbuf[32768 + row] + Lbuf[49152 + row];
        float inv = 1.f / lsum;
        f32x4 o = *reinterpret_cast<const f32x4*>(&outO[(size_t)row * HD + col]);
        #pragma unroll
        for (int cc = 0; cc < 3; ++cc) {
            ushort4 uu = *reinterpret_cast<const ushort4*>(
                &Obf[(size_t)cc * 2097152 + (size_t)row * HD + col]);
            union { u32 u; float f; } a, b2, c2, d2;
            a.u = (u32)uu.x << 16; b2.u = (u32)uu.y << 16;
            c2.u = (u32)uu.z << 16; d2.u = (u32)uu.w << 16;
            o[0] += a.f; o[1] += b2.f; o[2] += c2.f; o[3] += d2.f;
        }
        #pragma unroll
        for (int j = 0; j < 4; ++j) o[j] *= inv;
        *reinterpret_cast<f32x4*>(&outO[(size_t)row * HD + col]) = o;
    }
}

// ---------------------------------------------------------------------------
extern "C" void kernel_launch(void* const* d_in, const int* in_sizes, int n_in,
                              void* d_out, int out_size, void* d_ws, size_t ws_size,
                              hipStream_t stream) {
    const float* x  = (const float*)d_in[0];
    const float* Wq = (const float*)d_in[1];
    const float* Wk = (const float*)d_in[2];
    const float* Wv = (const float*)d_in[3];
    float* out = (float*)d_out;

    char* ws = (char*)d_ws;
    unsigned short* Qb  = (unsigned short*)(ws);                        // 4 MB
    unsigned short* Kb  = (unsigned short*)(ws + ((size_t)4  << 20));   // 4 MB
    unsigned short* Vt  = (unsigned short*)(ws + ((size_t)8  << 20));   // 4 MB
    unsigned short* Wt  = (unsigned short*)(ws + ((size_t)12 << 20));   // 768 KB
    unsigned short* Obf = (unsigned short*)(ws + ((size_t)13 << 20));   // 3 x 4 MB
    float*          Lb  = (float*)(ws + ((size_t)25 << 20));            // 4 x 64 KB

    wt_kernel   <<<dim3(16, 3),  dim3(256), 0, stream>>>(Wq, Wk, Wv, Wt);
    proj_kernel <<<dim3(3, 256), dim3(256), 0, stream>>>(x, Wt, Qb, Kb, Vt);
    attn_kernel <<<dim3(1024),   dim3(256), 0, stream>>>(Qb, Kb, Vt, out, Obf, Lb);
    merge_kernel<<<dim3(512),    dim3(256), 0, stream>>>(out, Obf, Lb);
}

// Round 8
// 173.544 us; speedup vs baseline: 1.4910x; 1.4910x over previous
//
#include <hip/hip_runtime.h>
#include <hip/hip_bf16.h>
#include <math.h>

#define D_MODEL 1024
#define HD 128
#define SEQ 4096

typedef __bf16 bf16x8 __attribute__((ext_vector_type(8)));
typedef float f32x4 __attribute__((ext_vector_type(4)));
typedef unsigned int u32;
typedef u32 u32x4 __attribute__((ext_vector_type(4)));

__device__ __forceinline__ unsigned short f2bf(float f) {
    union { float f; u32 u; } c; c.f = f;
    u32 u = c.u;
    u = (u + 0x7fffu + ((u >> 16) & 1u)) >> 16;
    return (unsigned short)u;
}
__device__ __forceinline__ u32 pk2(float a, float b) {
    __hip_bfloat162 h = __float22bfloat162_rn(make_float2(a, b));
    union { __hip_bfloat162 h; u32 u; } c; c.h = h; return c.u;
}
// async global->LDS, 16B/lane; dest = wave-uniform base + lane*16
__device__ __forceinline__ void dma16(void* lds, const void* g) {
    __builtin_amdgcn_global_load_lds(
        (const __attribute__((address_space(1))) u32*)g,
        (__attribute__((address_space(3))) u32*)lds, 16, 0, 0);
}
// DMA completion is only tracked in the ISSUING wave's vmcnt. Cooperative
// staging (wave A reads rows wave B staged) is only sound if EVERY wave
// drains vmcnt(0) before the publishing s_barrier. Do it explicitly --
// relying on the compiler/HW to do it at the barrier proved racy (R7).
// 0x0F70 = vmcnt(0), expcnt(7)=nowait, lgkmcnt(15)=nowait (gfx9 encoding).
__device__ __forceinline__ void drain_dma() {
    __builtin_amdgcn_s_waitcnt(0x0F70);
}

// ---------------------------------------------------------------------------
// LDS-transposed W -> Wt[n][k] bf16, n in [0,384). Q slice pre-scaled by
// 1/sqrt(128)*log2(e): scores exit QK^T MFMA in the log2 domain.
__global__ __launch_bounds__(256)
void wt_kernel(const float* __restrict__ Wq, const float* __restrict__ Wk,
               const float* __restrict__ Wv, unsigned short* __restrict__ Wt) {
    __shared__ float wsf[64][129];
    const int t = threadIdx.x;
    const int k0 = blockIdx.x * 64;
    const int mat = blockIdx.y;
    const float* W = (mat == 0) ? Wq : (mat == 1) ? Wk : Wv;
    const float sc = (mat == 0) ? (0.08838834764831845f * 1.4426950408889634f) : 1.0f;
    {
        const int r = t >> 2, c = (t & 3) * 32;
        const float* src = W + (size_t)(k0 + r) * HD + c;
        #pragma unroll
        for (int j = 0; j < 32; j += 4)
            *reinterpret_cast<f32x4*>(&wsf[r][c + j]) = *reinterpret_cast<const f32x4*>(src + j);
    }
    __syncthreads();
    const int n = t >> 1, ks = (t & 1) * 32;
    u32 ow[16];
    #pragma unroll
    for (int j = 0; j < 16; ++j)
        ow[j] = pk2(wsf[ks + 2 * j][n] * sc, wsf[ks + 2 * j + 1][n] * sc);
    unsigned short* dst = Wt + (size_t)(mat * HD + n) * D_MODEL + k0 + ks;
    #pragma unroll
    for (int j = 0; j < 4; ++j)
        *reinterpret_cast<u32x4*>(dst + j * 8) = (u32x4){ow[4*j], ow[4*j+1], ow[4*j+2], ow[4*j+3]};
}

// ---------------------------------------------------------------------------
// QKV projection, m97-style DMA staging + explicit pre-barrier DMA drain.
__global__ __launch_bounds__(256)
void proj_kernel(const float* __restrict__ x, const unsigned short* __restrict__ Wt,
                 unsigned short* __restrict__ Qb, unsigned short* __restrict__ Kb,
                 unsigned short* __restrict__ Vt) {
    __shared__ __align__(1024) char ps[32768];   // x: [0,16K) bufs of 8K; Wt: [16K,32K)
    const int t = threadIdx.x;
    const int w = t >> 6, l = t & 63, li = l & 15, g2 = l >> 4;
    const int nbase = blockIdx.x * 128;
    const int rowbase = blockIdx.y * 64;

    f32x4 acc[8];
    #pragma unroll
    for (int nt = 0; nt < 8; ++nt) acc[nt] = (f32x4){0.f, 0.f, 0.f, 0.f};

    const int lrow = l >> 3;                         // row within an 8-row issue
    const int xg = (l & 7) ^ (lrow & 6);             // x source granule
    const int wgr = (l & 7) ^ lrow;                  // Wt raw granule
    const int wrow_add = (wgr >> 2) << 6;            // +64 rows for upper k-half
    const int wkc = (wgr & 3) * 8;

    auto stage = [&](int k0, int buf) {
        #pragma unroll
        for (int j = 0; j < 2; ++j) {
            int r0 = w * 16 + 8 * j;
            dma16(ps + buf * 8192 + r0 * 128,
                  x + (size_t)(rowbase + r0 + lrow) * D_MODEL + k0 + xg * 4);
            dma16(ps + 16384 + buf * 8192 + r0 * 128,
                  Wt + (size_t)(nbase + r0 + lrow + wrow_add) * D_MODEL + k0 + wkc);
        }
    };

    stage(0, 0);
    for (int it = 0; it < 32; ++it) {
        const int buf = it & 1;
        drain_dma();           // publish this wave's DMA before the barrier
        __syncthreads();
        if (it + 1 < 32) stage((it + 1) * 32, buf ^ 1);
        const char* xb = ps + buf * 8192 + (w * 16 + li) * 128 + (((2 * g2) ^ (li & 6)) * 16);
        f32x4 x0 = *reinterpret_cast<const f32x4*>(xb);
        f32x4 x1 = *reinterpret_cast<const f32x4*>(xb + 16);
        union { u32 d[4]; bf16x8 v; } cva;
        cva.d[0] = pk2(x0[0], x0[1]); cva.d[1] = pk2(x0[2], x0[3]);
        cva.d[2] = pk2(x1[0], x1[1]); cva.d[3] = pk2(x1[2], x1[3]);
        bf16x8 af = cva.v;
        #pragma unroll
        for (int nt = 0; nt < 8; ++nt) {
            bf16x8 bfr = *reinterpret_cast<const bf16x8*>(
                ps + 16384 + buf * 8192 + ((nt & 3) * 16 + li) * 128 +
                ((((nt >> 2) * 4 + g2) ^ (li & 7)) * 16));
            acc[nt] = __builtin_amdgcn_mfma_f32_16x16x32_bf16(af, bfr, acc[nt], 0, 0, 0);
        }
    }

    if (nbase < 256) {
        unsigned short* P = nbase ? Kb : Qb;
        #pragma unroll
        for (int nt = 0; nt < 8; ++nt)
            #pragma unroll
            for (int r = 0; r < 4; ++r) {
                int grow = rowbase + w * 16 + g2 * 4 + r;
                P[(size_t)grow * HD + nt * 16 + li] = f2bf(acc[nt][r]);
            }
    } else {
        int grow0 = rowbase + w * 16 + g2 * 4;
        int b_ = grow0 >> 12, s_ = grow0 & 4095;
        #pragma unroll
        for (int nt = 0; nt < 8; ++nt) {
            ushort4 s4;
            s4.x = f2bf(acc[nt][0]); s4.y = f2bf(acc[nt][1]);
            s4.z = f2bf(acc[nt][2]); s4.w = f2bf(acc[nt][3]);
            *reinterpret_cast<ushort4*>(&Vt[((size_t)b_ * HD + nt * 16 + li) * SEQ + s_]) = s4;
        }
    }
}

// ---------------------------------------------------------------------------
// Flash causal attention (R6 structure, (256,2) bounds) + explicit DMA drain
// before the publishing barrier (barrier A).
__global__ __launch_bounds__(256, 2)
void attn_kernel(const unsigned short* __restrict__ Qb, const unsigned short* __restrict__ Kb,
                 const unsigned short* __restrict__ Vt, float* __restrict__ outO,
                 unsigned short* __restrict__ Obf, float* __restrict__ Lbuf) {
    __shared__ __align__(1024) char smem[40960];
    const int t = threadIdx.x;
    const int w = t >> 6, l = t & 63, li = l & 15, g2 = l >> 4;
    const int qh = w >> 1, kh = w & 1;
    const int b = blockIdx.x & 3;
    const int u = blockIdx.x >> 2;
    const int g = 63 - (u >> 2);               // q-group, heavy first
    const int c = u & 3;                       // key-range chunk
    const int R = g + 1;
    const int ts = (c * R) >> 2, te = ((c + 1) * R) >> 2;
    const int q0 = g * 64;
    const size_t rowb = (size_t)b * SEQ;
    const int koff = kh * 32;

    const unsigned short* KbB = Kb + rowb * HD;
    const unsigned short* VtB = Vt + (size_t)b * HD * SEQ;
    const int vgran = ((l & 7) ^ (l >> 3)) * 8;

    auto stage = [&](int it) {
        const int j0 = it * 64;
        #pragma unroll
        for (int j = 0; j < 4; ++j) {
            int rK = w * 16 + 4 * j + (l >> 4);
            dma16(smem + (w * 16 + 4 * j) * 256,
                  KbB + (size_t)(j0 + rK) * 128 + (((l & 15) ^ (rK & 7)) * 8));
            int rV = w * 32 + 8 * j + (l >> 3);
            dma16(smem + 16384 + (w * 32 + 8 * j) * 128,
                  VtB + (size_t)rV * SEQ + j0 + vgran);
        }
    };

    bf16x8 qf[2][4];
    #pragma unroll
    for (int qt = 0; qt < 2; ++qt)
        #pragma unroll
        for (int ks = 0; ks < 4; ++ks)
            qf[qt][ks] = *reinterpret_cast<const bf16x8*>(
                Qb + (rowb + q0 + qh * 32 + qt * 16 + li) * HD + ks * 32 + g2 * 8);

    f32x4 acco[2][8];
    #pragma unroll
    for (int qt = 0; qt < 2; ++qt)
        #pragma unroll
        for (int dt = 0; dt < 8; ++dt) acco[qt][dt] = (f32x4){0.f, 0.f, 0.f, 0.f};
    float ls[2][4] = {{0.f,0.f,0.f,0.f},{0.f,0.f,0.f,0.f}};

    const int gV = ((4 * kh + g2) ^ (li & 7)) * 16;   // V and P read granule offset

    if (ts < te) stage(ts);
    for (int it = ts; it < te; ++it) {
        drain_dma();       // publish this wave's DMA before the barrier
        __syncthreads();

        f32x4 accs[2][2];
        #pragma unroll
        for (int qt = 0; qt < 2; ++qt)
            #pragma unroll
            for (int kt = 0; kt < 2; ++kt) accs[qt][kt] = (f32x4){0.f, 0.f, 0.f, 0.f};
        #pragma unroll
        for (int kt = 0; kt < 2; ++kt) {
            const char* kb = smem + (koff + kt * 16 + li) * 256;
            #pragma unroll
            for (int ks = 0; ks < 4; ++ks) {
                bf16x8 kf = *reinterpret_cast<const bf16x8*>(kb + (((4 * ks + g2) ^ (li & 7)) * 16));
                accs[0][kt] = __builtin_amdgcn_mfma_f32_16x16x32_bf16(qf[0][ks], kf, accs[0][kt], 0, 0, 0);
                accs[1][kt] = __builtin_amdgcn_mfma_f32_16x16x32_bf16(qf[1][ks], kf, accs[1][kt], 0, 0, 0);
            }
        }

        const bool masked = (it == g);
        #pragma unroll
        for (int qt = 0; qt < 2; ++qt)
            #pragma unroll
            for (int kt = 0; kt < 2; ++kt)
                #pragma unroll
                for (int r = 0; r < 4; ++r) {
                    float s = accs[qt][kt][r];
                    if (masked && (koff + kt * 16 + li > qh * 32 + qt * 16 + g2 * 4 + r))
                        s = -INFINITY;
                    float p = __builtin_amdgcn_exp2f(s - 16.0f);
                    ls[qt][r] += p;
                    int prow = qh * 32 + qt * 16 + g2 * 4 + r;
                    int gw = (4 * kh + 2 * kt + (li >> 3)) ^ ((4 * g2 + r) & 7);
                    *reinterpret_cast<unsigned short*>(
                        smem + 32768 + prow * 128 + gw * 16 + (li & 7) * 2) = f2bf(p);
                }

        bf16x8 pf0 = *reinterpret_cast<const bf16x8*>(smem + 32768 + (qh * 32 + li) * 128 + gV);
        bf16x8 pf1 = *reinterpret_cast<const bf16x8*>(smem + 32768 + (qh * 32 + 16 + li) * 128 + gV);
        #pragma unroll
        for (int dt = 0; dt < 8; ++dt) {
            bf16x8 vf = *reinterpret_cast<const bf16x8*>(smem + 16384 + (dt * 16 + li) * 128 + gV);
            acco[0][dt] = __builtin_amdgcn_mfma_f32_16x16x32_bf16(pf0, vf, acco[0][dt], 0, 0, 0);
            acco[1][dt] = __builtin_amdgcn_mfma_f32_16x16x32_bf16(pf1, vf, acco[1][dt], 0, 0, 0);
        }
        __syncthreads();   // all reads of K/V/P done before restaging
        if (it + 1 < te) stage(it + 1);
    }

    // per-lane l -> per-row l (16 key-lanes)
    #pragma unroll
    for (int d = 1; d < 16; d <<= 1)
        #pragma unroll
        for (int qt = 0; qt < 2; ++qt)
            #pragma unroll
            for (int r = 0; r < 4; ++r)
                ls[qt][r] += __shfl_xor(ls[qt][r], d);

    // combine kh halves via LDS overlay (stage buffers dead now)
    float (*Osum)[132] = (float(*)[132])smem;        // 64 x 128 (+4 pad) f32
    float* Lsh = (float*)(smem + 33792);             // [2][64]
    __syncthreads();
    if (kh == 0) {
        #pragma unroll
        for (int qt = 0; qt < 2; ++qt) {
            #pragma unroll
            for (int dt = 0; dt < 8; ++dt)
                #pragma unroll
                for (int r = 0; r < 4; ++r)
                    Osum[qh * 32 + qt * 16 + g2 * 4 + r][dt * 16 + li] = acco[qt][dt][r];
            if (li == 0)
                #pragma unroll
                for (int r = 0; r < 4; ++r)
                    Lsh[qh * 32 + qt * 16 + g2 * 4 + r] = ls[qt][r];
        }
    }
    __syncthreads();
    if (kh == 1) {
        #pragma unroll
        for (int qt = 0; qt < 2; ++qt) {
            #pragma unroll
            for (int dt = 0; dt < 8; ++dt)
                #pragma unroll
                for (int r = 0; r < 4; ++r)
                    Osum[qh * 32 + qt * 16 + g2 * 4 + r][dt * 16 + li] += acco[qt][dt][r];
            if (li == 0)
                #pragma unroll
                for (int r = 0; r < 4; ++r)
                    Lsh[64 + qh * 32 + qt * 16 + g2 * 4 + r] = ls[qt][r];
        }
    }
    __syncthreads();

    if (t < 64)
        Lbuf[(size_t)c * 16384 + rowb + q0 + t] = Lsh[t] + Lsh[64 + t];
    #pragma unroll
    for (int k = 0; k < 8; ++k) {
        int idx = t + k * 256;
        int row = idx >> 5, col = (idx & 31) * 4;
        f32x4 o = *reinterpret_cast<const f32x4*>(&Osum[row][col]);
        size_t grow = rowb + q0 + row;
        if (c == 3) {
            *reinterpret_cast<f32x4*>(&outO[grow * HD + col]) = o;
        } else {
            union { u32 d[2]; uint2 v; } pkd;
            pkd.d[0] = pk2(o[0], o[1]); pkd.d[1] = pk2(o[2], o[3]);
            *reinterpret_cast<uint2*>(&Obf[(size_t)c * 2097152 + grow * HD + col]) = pkd.v;
        }
    }
}

// ---------------------------------------------------------------------------
// Merge: out = (Obf[0]+Obf[1]+Obf[2]+out) / (l0+l1+l2+l3)
__global__ __launch_bounds__(256)
void merge_kernel(float* __restrict__ outO, const unsigned short* __restrict__ Obf,
                  const float* __restrict__ Lbuf) {
    int tid = blockIdx.x * 256 + threadIdx.x;
    #pragma unroll
    for (int k = 0; k < 4; ++k) {
        int idx = tid + k * 131072;
        int row = idx >> 5, col = (idx & 31) * 4;
        float lsum = Lbuf[row] + Lbuf[16384 + row] + Lbuf[32768 + row] + Lbuf[49152 + row];
        float inv = 1.f / lsum;
        f32x4 o = *reinterpret_cast<const f32x4*>(&outO[(size_t)row * HD + col]);
        #pragma unroll
        for (int cc = 0; cc < 3; ++cc) {
            ushort4 uu = *reinterpret_cast<const ushort4*>(
                &Obf[(size_t)cc * 2097152 + (size_t)row * HD + col]);
            union { u32 u; float f; } a, b2, c2, d2;
            a.u = (u32)uu.x << 16; b2.u = (u32)uu.y << 16;
            c2.u = (u32)uu.z << 16; d2.u = (u32)uu.w << 16;
            o[0] += a.f; o[1] += b2.f; o[2] += c2.f; o[3] += d2.f;
        }
        #pragma unroll
        for (int j = 0; j < 4; ++j) o[j] *= inv;
        *reinterpret_cast<f32x4*>(&outO[(size_t)row * HD + col]) = o;
    }
}

// ---------------------------------------------------------------------------
extern "C" void kernel_launch(void* const* d_in, const int* in_sizes, int n_in,
                              void* d_out, int out_size, void* d_ws, size_t ws_size,
                              hipStream_t stream) {
    const float* x  = (const float*)d_in[0];
    const float* Wq = (const float*)d_in[1];
    const float* Wk = (const float*)d_in[2];
    const float* Wv = (const float*)d_in[3];
    float* out = (float*)d_out;

    char* ws = (char*)d_ws;
    unsigned short* Qb  = (unsigned short*)(ws);                        // 4 MB
    unsigned short* Kb  = (unsigned short*)(ws + ((size_t)4  << 20));   // 4 MB
    unsigned short* Vt  = (unsigned short*)(ws + ((size_t)8  << 20));   // 4 MB
    unsigned short* Wt  = (unsigned short*)(ws + ((size_t)12 << 20));   // 768 KB
    unsigned short* Obf = (unsigned short*)(ws + ((size_t)13 << 20));   // 3 x 4 MB
    float*          Lb  = (float*)(ws + ((size_t)25 << 20));            // 4 x 64 KB

    wt_kernel   <<<dim3(16, 3),  dim3(256), 0, stream>>>(Wq, Wk, Wv, Wt);
    proj_kernel <<<dim3(3, 256), dim3(256), 0, stream>>>(x, Wt, Qb, Kb, Vt);
    attn_kernel <<<dim3(1024),   dim3(256), 0, stream>>>(Qb, Kb, Vt, out, Obf, Lb);
    merge_kernel<<<dim3(512),    dim3(256), 0, stream>>>(out, Obf, Lb);
}

// Round 9
// 169.549 us; speedup vs baseline: 1.5262x; 1.0236x over previous
//
#include <hip/hip_runtime.h>
#include <hip/hip_bf16.h>
#include <math.h>

#define D_MODEL 1024
#define HD 128
#define SEQ 4096

typedef __bf16 bf16x8 __attribute__((ext_vector_type(8)));
typedef float f32x4 __attribute__((ext_vector_type(4)));
typedef unsigned int u32;
typedef u32 u32x4 __attribute__((ext_vector_type(4)));

__device__ __forceinline__ unsigned short f2bf(float f) {
    union { float f; u32 u; } c; c.f = f;
    u32 u = c.u;
    u = (u + 0x7fffu + ((u >> 16) & 1u)) >> 16;
    return (unsigned short)u;
}
__device__ __forceinline__ u32 pk2(float a, float b) {
    __hip_bfloat162 h = __float22bfloat162_rn(make_float2(a, b));
    union { __hip_bfloat162 h; u32 u; } c; c.h = h; return c.u;
}
// async global->LDS, 16B/lane; dest = wave-uniform base + lane*16
__device__ __forceinline__ void dma16(void* lds, const void* g) {
    __builtin_amdgcn_global_load_lds(
        (const __attribute__((address_space(1))) u32*)g,
        (__attribute__((address_space(3))) u32*)lds, 16, 0, 0);
}
// DMA completion is tracked only in the ISSUING wave's vmcnt; cooperative
// staging requires every wave to drain vmcnt(0) before the publishing
// barrier (R7 proved relying on the compiler is racy).
__device__ __forceinline__ void drain_dma() {
    __builtin_amdgcn_s_waitcnt(0x0F70);   // vmcnt(0), expcnt/lgkmcnt nowait
}

// ---------------------------------------------------------------------------
// LDS-transposed W -> Wt[n][k] bf16, n in [0,384). Q slice pre-scaled by
// 1/sqrt(128)*log2(e): scores exit QK^T MFMA in the log2 domain.
__global__ __launch_bounds__(256)
void wt_kernel(const float* __restrict__ Wq, const float* __restrict__ Wk,
               const float* __restrict__ Wv, unsigned short* __restrict__ Wt) {
    __shared__ float wsf[64][129];
    const int t = threadIdx.x;
    const int k0 = blockIdx.x * 64;
    const int mat = blockIdx.y;
    const float* W = (mat == 0) ? Wq : (mat == 1) ? Wk : Wv;
    const float sc = (mat == 0) ? (0.08838834764831845f * 1.4426950408889634f) : 1.0f;
    {
        const int r = t >> 2, c = (t & 3) * 32;
        const float* src = W + (size_t)(k0 + r) * HD + c;
        #pragma unroll
        for (int j = 0; j < 32; j += 4)
            *reinterpret_cast<f32x4*>(&wsf[r][c + j]) = *reinterpret_cast<const f32x4*>(src + j);
    }
    __syncthreads();
    const int n = t >> 1, ks = (t & 1) * 32;
    u32 ow[16];
    #pragma unroll
    for (int j = 0; j < 16; ++j)
        ow[j] = pk2(wsf[ks + 2 * j][n] * sc, wsf[ks + 2 * j + 1][n] * sc);
    unsigned short* dst = Wt + (size_t)(mat * HD + n) * D_MODEL + k0 + ks;
    #pragma unroll
    for (int j = 0; j < 4; ++j)
        *reinterpret_cast<u32x4*>(dst + j * 8) = (u32x4){ow[4*j], ow[4*j+1], ow[4*j+2], ow[4*j+3]};
}

// ---------------------------------------------------------------------------
// QKV projection, DMA staging + XCD-aware swizzle: the 3 n-slice siblings of
// each m-tile are spaced exactly 8 block-ids apart so they land on the SAME
// XCD (round-robin id%8) and share the x tile via that XCD's L2.
__global__ __launch_bounds__(256)
void proj_kernel(const float* __restrict__ x, const unsigned short* __restrict__ Wt,
                 unsigned short* __restrict__ Qb, unsigned short* __restrict__ Kb,
                 unsigned short* __restrict__ Vt) {
    __shared__ __align__(1024) char ps[32768];   // x: [0,16K) bufs of 8K; Wt: [16K,32K)
    const int t = threadIdx.x;
    const int w = t >> 6, l = t & 63, li = l & 15, g2 = l >> 4;
    const int id = blockIdx.x;                 // 0..767
    const int grp = id / 24, win = id % 24;
    const int nbase = (win >> 3) * 128;        // slice 0:Q 1:K 2:V
    const int rowbase = (grp * 8 + (win & 7)) * 64;

    f32x4 acc[8];
    #pragma unroll
    for (int nt = 0; nt < 8; ++nt) acc[nt] = (f32x4){0.f, 0.f, 0.f, 0.f};

    const int lrow = l >> 3;                         // row within an 8-row issue
    const int xg = (l & 7) ^ (lrow & 6);             // x source granule
    const int wgr = (l & 7) ^ lrow;                  // Wt raw granule
    const int wrow_add = (wgr >> 2) << 6;            // +64 rows for upper k-half
    const int wkc = (wgr & 3) * 8;

    auto stage = [&](int k0, int buf) {
        #pragma unroll
        for (int j = 0; j < 2; ++j) {
            int r0 = w * 16 + 8 * j;
            dma16(ps + buf * 8192 + r0 * 128,
                  x + (size_t)(rowbase + r0 + lrow) * D_MODEL + k0 + xg * 4);
            dma16(ps + 16384 + buf * 8192 + r0 * 128,
                  Wt + (size_t)(nbase + r0 + lrow + wrow_add) * D_MODEL + k0 + wkc);
        }
    };

    stage(0, 0);
    for (int it = 0; it < 32; ++it) {
        const int buf = it & 1;
        drain_dma();           // publish this wave's DMA before the barrier
        __syncthreads();
        if (it + 1 < 32) stage((it + 1) * 32, buf ^ 1);
        const char* xb = ps + buf * 8192 + (w * 16 + li) * 128 + (((2 * g2) ^ (li & 6)) * 16);
        f32x4 x0 = *reinterpret_cast<const f32x4*>(xb);
        f32x4 x1 = *reinterpret_cast<const f32x4*>(xb + 16);
        union { u32 d[4]; bf16x8 v; } cva;
        cva.d[0] = pk2(x0[0], x0[1]); cva.d[1] = pk2(x0[2], x0[3]);
        cva.d[2] = pk2(x1[0], x1[1]); cva.d[3] = pk2(x1[2], x1[3]);
        bf16x8 af = cva.v;
        #pragma unroll
        for (int nt = 0; nt < 8; ++nt) {
            bf16x8 bfr = *reinterpret_cast<const bf16x8*>(
                ps + 16384 + buf * 8192 + ((nt & 3) * 16 + li) * 128 +
                ((((nt >> 2) * 4 + g2) ^ (li & 7)) * 16));
            acc[nt] = __builtin_amdgcn_mfma_f32_16x16x32_bf16(af, bfr, acc[nt], 0, 0, 0);
        }
    }

    if (nbase < 256) {
        unsigned short* P = nbase ? Kb : Qb;
        #pragma unroll
        for (int nt = 0; nt < 8; ++nt)
            #pragma unroll
            for (int r = 0; r < 4; ++r) {
                int grow = rowbase + w * 16 + g2 * 4 + r;
                P[(size_t)grow * HD + nt * 16 + li] = f2bf(acc[nt][r]);
            }
    } else {
        int grow0 = rowbase + w * 16 + g2 * 4;
        int b_ = grow0 >> 12, s_ = grow0 & 4095;
        #pragma unroll
        for (int nt = 0; nt < 8; ++nt) {
            ushort4 s4;
            s4.x = f2bf(acc[nt][0]); s4.y = f2bf(acc[nt][1]);
            s4.z = f2bf(acc[nt][2]); s4.w = f2bf(acc[nt][3]);
            *reinterpret_cast<ushort4*>(&Vt[((size_t)b_ * HD + nt * 16 + li) * SEQ + s_]) = s4;
        }
    }
}

// ---------------------------------------------------------------------------
// Flash causal attention with DOUBLE-BUFFERED K/V DMA staging: one barrier
// per iter; stage(it+1) is issued right after the barrier so its latency is
// hidden behind the full compute of iter it (R8 issued it right before the
// drain -- zero overlap, ~900 cyc exposed per iter).
// LDS 72 KB: K/V buf0 [0,32K), K/V buf1 [32K,64K), P [64K,72K).
__global__ __launch_bounds__(256, 2)
void attn_kernel(const unsigned short* __restrict__ Qb, const unsigned short* __restrict__ Kb,
                 const unsigned short* __restrict__ Vt, float* __restrict__ outO,
                 unsigned short* __restrict__ Obf, float* __restrict__ Lbuf) {
    __shared__ __align__(1024) char smem[73728];
    const int t = threadIdx.x;
    const int w = t >> 6, l = t & 63, li = l & 15, g2 = l >> 4;
    const int qh = w >> 1, kh = w & 1;
    const int b = blockIdx.x & 3;
    const int u = blockIdx.x >> 2;
    const int g = 63 - (u >> 2);               // q-group, heavy first
    const int c = u & 3;                       // key-range chunk
    const int R = g + 1;
    const int ts = (c * R) >> 2, te = ((c + 1) * R) >> 2;
    const int q0 = g * 64;
    const size_t rowb = (size_t)b * SEQ;
    const int koff = kh * 32;

    const unsigned short* KbB = Kb + rowb * HD;
    const unsigned short* VtB = Vt + (size_t)b * HD * SEQ;
    const int vgran = ((l & 7) ^ (l >> 3)) * 8;

    auto stage = [&](int it, char* base) {
        const int j0 = it * 64;
        #pragma unroll
        for (int j = 0; j < 4; ++j) {
            int rK = w * 16 + 4 * j + (l >> 4);
            dma16(base + (w * 16 + 4 * j) * 256,
                  KbB + (size_t)(j0 + rK) * 128 + (((l & 15) ^ (rK & 7)) * 8));
            int rV = w * 32 + 8 * j + (l >> 3);
            dma16(base + 16384 + (w * 32 + 8 * j) * 128,
                  VtB + (size_t)rV * SEQ + j0 + vgran);
        }
    };

    bf16x8 qf[2][4];
    #pragma unroll
    for (int qt = 0; qt < 2; ++qt)
        #pragma unroll
        for (int ks = 0; ks < 4; ++ks)
            qf[qt][ks] = *reinterpret_cast<const bf16x8*>(
                Qb + (rowb + q0 + qh * 32 + qt * 16 + li) * HD + ks * 32 + g2 * 8);

    f32x4 acco[2][8];
    #pragma unroll
    for (int qt = 0; qt < 2; ++qt)
        #pragma unroll
        for (int dt = 0; dt < 8; ++dt) acco[qt][dt] = (f32x4){0.f, 0.f, 0.f, 0.f};
    float ls[2][4] = {{0.f,0.f,0.f,0.f},{0.f,0.f,0.f,0.f}};

    const int gV = ((4 * kh + g2) ^ (li & 7)) * 16;   // V and P read granule offset

    if (ts < te) stage(ts, smem);
    for (int it = ts; it < te; ++it) {
        char* cbuf = smem + ((it - ts) & 1) * 32768;
        char* nbuf = smem + (((it - ts) & 1) ^ 1) * 32768;
        drain_dma();       // publish this wave's DMA (issued last iter)
        __syncthreads();   // all waves' stage(it) visible; buf^1 reads done
        if (it + 1 < te) stage(it + 1, nbuf);   // overlaps compute below

        f32x4 accs[2][2];
        #pragma unroll
        for (int qt = 0; qt < 2; ++qt)
            #pragma unroll
            for (int kt = 0; kt < 2; ++kt) accs[qt][kt] = (f32x4){0.f, 0.f, 0.f, 0.f};
        #pragma unroll
        for (int kt = 0; kt < 2; ++kt) {
            const char* kb = cbuf + (koff + kt * 16 + li) * 256;
            #pragma unroll
            for (int ks = 0; ks < 4; ++ks) {
                bf16x8 kf = *reinterpret_cast<const bf16x8*>(kb + (((4 * ks + g2) ^ (li & 7)) * 16));
                accs[0][kt] = __builtin_amdgcn_mfma_f32_16x16x32_bf16(qf[0][ks], kf, accs[0][kt], 0, 0, 0);
                accs[1][kt] = __builtin_amdgcn_mfma_f32_16x16x32_bf16(qf[1][ks], kf, accs[1][kt], 0, 0, 0);
            }
        }

        const bool masked = (it == g);
        #pragma unroll
        for (int qt = 0; qt < 2; ++qt)
            #pragma unroll
            for (int kt = 0; kt < 2; ++kt)
                #pragma unroll
                for (int r = 0; r < 4; ++r) {
                    float s = accs[qt][kt][r];
                    if (masked && (koff + kt * 16 + li > qh * 32 + qt * 16 + g2 * 4 + r))
                        s = -INFINITY;
                    float p = __builtin_amdgcn_exp2f(s - 16.0f);
                    ls[qt][r] += p;
                    int prow = qh * 32 + qt * 16 + g2 * 4 + r;
                    int gw = (4 * kh + 2 * kt + (li >> 3)) ^ ((4 * g2 + r) & 7);
                    *reinterpret_cast<unsigned short*>(
                        smem + 65536 + prow * 128 + gw * 16 + (li & 7) * 2) = f2bf(p);
                }

        // P write->read is in-wave only (each wave reads exactly the granules
        // it wrote); compiler orders via lgkmcnt. No barrier needed.
        bf16x8 pf0 = *reinterpret_cast<const bf16x8*>(smem + 65536 + (qh * 32 + li) * 128 + gV);
        bf16x8 pf1 = *reinterpret_cast<const bf16x8*>(smem + 65536 + (qh * 32 + 16 + li) * 128 + gV);
        #pragma unroll
        for (int dt = 0; dt < 8; ++dt) {
            bf16x8 vf = *reinterpret_cast<const bf16x8*>(cbuf + 16384 + (dt * 16 + li) * 128 + gV);
            acco[0][dt] = __builtin_amdgcn_mfma_f32_16x16x32_bf16(pf0, vf, acco[0][dt], 0, 0, 0);
            acco[1][dt] = __builtin_amdgcn_mfma_f32_16x16x32_bf16(pf1, vf, acco[1][dt], 0, 0, 0);
        }
    }

    // per-lane l -> per-row l (16 key-lanes)
    #pragma unroll
    for (int d = 1; d < 16; d <<= 1)
        #pragma unroll
        for (int qt = 0; qt < 2; ++qt)
            #pragma unroll
            for (int r = 0; r < 4; ++r)
                ls[qt][r] += __shfl_xor(ls[qt][r], d);

    // combine kh halves via LDS overlay (stage buffers dead now)
    float (*Osum)[132] = (float(*)[132])smem;        // 64 x 128 (+4 pad) f32
    float* Lsh = (float*)(smem + 33792);             // [2][64]
    __syncthreads();
    if (kh == 0) {
        #pragma unroll
        for (int qt = 0; qt < 2; ++qt) {
            #pragma unroll
            for (int dt = 0; dt < 8; ++dt)
                #pragma unroll
                for (int r = 0; r < 4; ++r)
                    Osum[qh * 32 + qt * 16 + g2 * 4 + r][dt * 16 + li] = acco[qt][dt][r];
            if (li == 0)
                #pragma unroll
                for (int r = 0; r < 4; ++r)
                    Lsh[qh * 32 + qt * 16 + g2 * 4 + r] = ls[qt][r];
        }
    }
    __syncthreads();
    if (kh == 1) {
        #pragma unroll
        for (int qt = 0; qt < 2; ++qt) {
            #pragma unroll
            for (int dt = 0; dt < 8; ++dt)
                #pragma unroll
                for (int r = 0; r < 4; ++r)
                    Osum[qh * 32 + qt * 16 + g2 * 4 + r][dt * 16 + li] += acco[qt][dt][r];
            if (li == 0)
                #pragma unroll
                for (int r = 0; r < 4; ++r)
                    Lsh[64 + qh * 32 + qt * 16 + g2 * 4 + r] = ls[qt][r];
        }
    }
    __syncthreads();

    if (t < 64)
        Lbuf[(size_t)c * 16384 + rowb + q0 + t] = Lsh[t] + Lsh[64 + t];
    #pragma unroll
    for (int k = 0; k < 8; ++k) {
        int idx = t + k * 256;
        int row = idx >> 5, col = (idx & 31) * 4;
        f32x4 o = *reinterpret_cast<const f32x4*>(&Osum[row][col]);
        size_t grow = rowb + q0 + row;
        if (c == 3) {
            *reinterpret_cast<f32x4*>(&outO[grow * HD + col]) = o;
        } else {
            union { u32 d[2]; uint2 v; } pkd;
            pkd.d[0] = pk2(o[0], o[1]); pkd.d[1] = pk2(o[2], o[3]);
            *reinterpret_cast<uint2*>(&Obf[(size_t)c * 2097152 + grow * HD + col]) = pkd.v;
        }
    }
}

// ---------------------------------------------------------------------------
// Merge: out = (Obf[0]+Obf[1]+Obf[2]+out) / (l0+l1+l2+l3)
__global__ __launch_bounds__(256)
void merge_kernel(float* __restrict__ outO, const unsigned short* __restrict__ Obf,
                  const float* __restrict__ Lbuf) {
    int tid = blockIdx.x * 256 + threadIdx.x;
    #pragma unroll
    for (int k = 0; k < 4; ++k) {
        int idx = tid + k * 131072;
        int row = idx >> 5, col = (idx & 31) * 4;
        float lsum = Lbuf[row] + Lbuf[16384 + row] + Lbuf[32768 + row] + Lbuf[49152 + row];
        float inv = 1.f / lsum;
        f32x4 o = *reinterpret_cast<const f32x4*>(&outO[(size_t)row * HD + col]);
        #pragma unroll
        for (int cc = 0; cc < 3; ++cc) {
            ushort4 uu = *reinterpret_cast<const ushort4*>(
                &Obf[(size_t)cc * 2097152 + (size_t)row * HD + col]);
            union { u32 u; float f; } a, b2, c2, d2;
            a.u = (u32)uu.x << 16; b2.u = (u32)uu.y << 16;
            c2.u = (u32)uu.z << 16; d2.u = (u32)uu.w << 16;
            o[0] += a.f; o[1] += b2.f; o[2] += c2.f; o[3] += d2.f;
        }
        #pragma unroll
        for (int j = 0; j < 4; ++j) o[j] *= inv;
        *reinterpret_cast<f32x4*>(&outO[(size_t)row * HD + col]) = o;
    }
}

// ---------------------------------------------------------------------------
extern "C" void kernel_launch(void* const* d_in, const int* in_sizes, int n_in,
                              void* d_out, int out_size, void* d_ws, size_t ws_size,
                              hipStream_t stream) {
    const float* x  = (const float*)d_in[0];
    const float* Wq = (const float*)d_in[1];
    const float* Wk = (const float*)d_in[2];
    const float* Wv = (const float*)d_in[3];
    float* out = (float*)d_out;

    char* ws = (char*)d_ws;
    unsigned short* Qb  = (unsigned short*)(ws);                        // 4 MB
    unsigned short* Kb  = (unsigned short*)(ws + ((size_t)4  << 20));   // 4 MB
    unsigned short* Vt  = (unsigned short*)(ws + ((size_t)8  << 20));   // 4 MB
    unsigned short* Wt  = (unsigned short*)(ws + ((size_t)12 << 20));   // 768 KB
    unsigned short* Obf = (unsigned short*)(ws + ((size_t)13 << 20));   // 3 x 4 MB
    float*          Lb  = (float*)(ws + ((size_t)25 << 20));            // 4 x 64 KB

    wt_kernel   <<<dim3(16, 3), dim3(256), 0, stream>>>(Wq, Wk, Wv, Wt);
    proj_kernel <<<dim3(768),   dim3(256), 0, stream>>>(x, Wt, Qb, Kb, Vt);
    attn_kernel <<<dim3(1024),  dim3(256), 0, stream>>>(Qb, Kb, Vt, out, Obf, Lb);
    merge_kernel<<<dim3(512),   dim3(256), 0, stream>>>(out, Obf, Lb);
}

// Round 10
// 165.942 us; speedup vs baseline: 1.5593x; 1.0217x over previous
//
#include <hip/hip_runtime.h>
#include <hip/hip_bf16.h>
#include <math.h>

#define D_MODEL 1024
#define HD 128
#define SEQ 4096

typedef __bf16 bf16x8 __attribute__((ext_vector_type(8)));
typedef float f32x4 __attribute__((ext_vector_type(4)));
typedef unsigned int u32;
typedef u32 u32x4 __attribute__((ext_vector_type(4)));

__device__ __forceinline__ unsigned short f2bf(float f) {
    union { float f; u32 u; } c; c.f = f;
    u32 u = c.u;
    u = (u + 0x7fffu + ((u >> 16) & 1u)) >> 16;
    return (unsigned short)u;
}
__device__ __forceinline__ u32 pk2(float a, float b) {
    __hip_bfloat162 h = __float22bfloat162_rn(make_float2(a, b));
    union { __hip_bfloat162 h; u32 u; } c; c.h = h; return c.u;
}
// async global->LDS, 16B/lane; dest = wave-uniform base + lane*16
__device__ __forceinline__ void dma16(void* lds, const void* g) {
    __builtin_amdgcn_global_load_lds(
        (const __attribute__((address_space(1))) u32*)g,
        (__attribute__((address_space(3))) u32*)lds, 16, 0, 0);
}
// DMA completion is tracked only in the ISSUING wave's vmcnt (R7 race).
__device__ __forceinline__ void drain_dma()  { __builtin_amdgcn_s_waitcnt(0x0F70); } // vmcnt(0)
// Wait until <=4 vmem outstanding: retires the OLDEST stage (4 DMA instrs),
// leaves the newest stage in flight -- enables prefetch distance 2.
__device__ __forceinline__ void drain_dma4() { __builtin_amdgcn_s_waitcnt(0x0F74); } // vmcnt(4)

// ---------------------------------------------------------------------------
// LDS-transposed W -> Wt[n][k] bf16, n in [0,384). Q slice pre-scaled by
// 1/sqrt(128)*log2(e): scores exit QK^T MFMA in the log2 domain.
__global__ __launch_bounds__(256)
void wt_kernel(const float* __restrict__ Wq, const float* __restrict__ Wk,
               const float* __restrict__ Wv, unsigned short* __restrict__ Wt) {
    __shared__ float wsf[64][129];
    const int t = threadIdx.x;
    const int k0 = blockIdx.x * 64;
    const int mat = blockIdx.y;
    const float* W = (mat == 0) ? Wq : (mat == 1) ? Wk : Wv;
    const float sc = (mat == 0) ? (0.08838834764831845f * 1.4426950408889634f) : 1.0f;
    {
        const int r = t >> 2, c = (t & 3) * 32;
        const float* src = W + (size_t)(k0 + r) * HD + c;
        #pragma unroll
        for (int j = 0; j < 32; j += 4)
            *reinterpret_cast<f32x4*>(&wsf[r][c + j]) = *reinterpret_cast<const f32x4*>(src + j);
    }
    __syncthreads();
    const int n = t >> 1, ks = (t & 1) * 32;
    u32 ow[16];
    #pragma unroll
    for (int j = 0; j < 16; ++j)
        ow[j] = pk2(wsf[ks + 2 * j][n] * sc, wsf[ks + 2 * j + 1][n] * sc);
    unsigned short* dst = Wt + (size_t)(mat * HD + n) * D_MODEL + k0 + ks;
    #pragma unroll
    for (int j = 0; j < 4; ++j)
        *reinterpret_cast<u32x4*>(dst + j * 8) = (u32x4){ow[4*j], ow[4*j+1], ow[4*j+2], ow[4*j+3]};
}

// ---------------------------------------------------------------------------
// QKV projection: DMA staging, XCD-aware swizzle (3 siblings of an m-tile are
// 8 ids apart -> same XCD L2), prefetch DISTANCE 2 via triple buffer +
// vmcnt(4) drain (distance 1 left ~600 cyc HBM latency exposed per iter, R9).
__global__ __launch_bounds__(256)
void proj_kernel(const float* __restrict__ x, const unsigned short* __restrict__ Wt,
                 unsigned short* __restrict__ Qb, unsigned short* __restrict__ Kb,
                 unsigned short* __restrict__ Vt) {
    __shared__ __align__(1024) char ps[49152];   // x: 3 bufs @ [0,24K); Wt: 3 bufs @ [24K,48K)
    const int t = threadIdx.x;
    const int w = t >> 6, l = t & 63, li = l & 15, g2 = l >> 4;
    const int id = blockIdx.x;                 // 0..767
    const int grp = id / 24, win = id % 24;
    const int nbase = (win >> 3) * 128;        // slice 0:Q 1:K 2:V
    const int rowbase = (grp * 8 + (win & 7)) * 64;

    f32x4 acc[8];
    #pragma unroll
    for (int nt = 0; nt < 8; ++nt) acc[nt] = (f32x4){0.f, 0.f, 0.f, 0.f};

    const int lrow = l >> 3;                         // row within an 8-row issue
    const int xg = (l & 7) ^ (lrow & 6);             // x source granule
    const int wgr = (l & 7) ^ lrow;                  // Wt raw granule
    const int wrow_add = (wgr >> 2) << 6;            // +64 rows for upper k-half
    const int wkc = (wgr & 3) * 8;

    auto stage = [&](int k0, int buf) {
        #pragma unroll
        for (int j = 0; j < 2; ++j) {
            int r0 = w * 16 + 8 * j;
            dma16(ps + buf * 8192 + r0 * 128,
                  x + (size_t)(rowbase + r0 + lrow) * D_MODEL + k0 + xg * 4);
            dma16(ps + 24576 + buf * 8192 + r0 * 128,
                  Wt + (size_t)(nbase + r0 + lrow + wrow_add) * D_MODEL + k0 + wkc);
        }
    };

    stage(0, 0);
    stage(32, 1);
    for (int it = 0; it < 32; ++it) {
        const int buf = it % 3;
        if (it < 31) drain_dma4(); else drain_dma();   // retire stage(it) only
        __syncthreads();
        if (it + 2 < 32) stage((it + 2) * 32, (it + 2) % 3);
        const char* xb = ps + buf * 8192 + (w * 16 + li) * 128 + (((2 * g2) ^ (li & 6)) * 16);
        f32x4 x0 = *reinterpret_cast<const f32x4*>(xb);
        f32x4 x1 = *reinterpret_cast<const f32x4*>(xb + 16);
        union { u32 d[4]; bf16x8 v; } cva;
        cva.d[0] = pk2(x0[0], x0[1]); cva.d[1] = pk2(x0[2], x0[3]);
        cva.d[2] = pk2(x1[0], x1[1]); cva.d[3] = pk2(x1[2], x1[3]);
        bf16x8 af = cva.v;
        #pragma unroll
        for (int nt = 0; nt < 8; ++nt) {
            bf16x8 bfr = *reinterpret_cast<const bf16x8*>(
                ps + 24576 + buf * 8192 + ((nt & 3) * 16 + li) * 128 +
                ((((nt >> 2) * 4 + g2) ^ (li & 7)) * 16));
            acc[nt] = __builtin_amdgcn_mfma_f32_16x16x32_bf16(af, bfr, acc[nt], 0, 0, 0);
        }
    }

    if (nbase < 256) {
        unsigned short* P = nbase ? Kb : Qb;
        #pragma unroll
        for (int nt = 0; nt < 8; ++nt)
            #pragma unroll
            for (int r = 0; r < 4; ++r) {
                int grow = rowbase + w * 16 + g2 * 4 + r;
                P[(size_t)grow * HD + nt * 16 + li] = f2bf(acc[nt][r]);
            }
    } else {
        int grow0 = rowbase + w * 16 + g2 * 4;
        int b_ = grow0 >> 12, s_ = grow0 & 4095;
        #pragma unroll
        for (int nt = 0; nt < 8; ++nt) {
            ushort4 s4;
            s4.x = f2bf(acc[nt][0]); s4.y = f2bf(acc[nt][1]);
            s4.z = f2bf(acc[nt][2]); s4.w = f2bf(acc[nt][3]);
            *reinterpret_cast<ushort4*>(&Vt[((size_t)b_ * HD + nt * 16 + li) * SEQ + s_]) = s4;
        }
    }
}

// ---------------------------------------------------------------------------
// Flash causal attention, OPERAND-SWAPPED: scores computed as K.Q^T so the
// C-layout gives each lane 4 CONTIGUOUS keys for one query column. Softmax
// row-sum becomes a per-lane scalar; P^T packs to one b64 LDS write per frag;
// PV runs as A=V(d,k), B=P^T(k,q); O exits q=lane/d-contiguous -> f32x4 stores.
// Double-buffered K/V DMA staging (one barrier/iter), fixed-shift softmax.
// LDS 72 KB: K/V buf0 [0,32K), buf1 [32K,64K), P^T [64K,72K).
__global__ __launch_bounds__(256, 2)
void attn_kernel(const unsigned short* __restrict__ Qb, const unsigned short* __restrict__ Kb,
                 const unsigned short* __restrict__ Vt, float* __restrict__ outO,
                 unsigned short* __restrict__ Obf, float* __restrict__ Lbuf) {
    __shared__ __align__(1024) char smem[73728];
    const int t = threadIdx.x;
    const int w = t >> 6, l = t & 63, li = l & 15, g2 = l >> 4;
    const int qh = w >> 1, kh = w & 1;
    const int b = blockIdx.x & 3;
    const int u = blockIdx.x >> 2;
    const int g = 63 - (u >> 2);               // q-group, heavy first (LPT)
    const int c = u & 3;                       // key-range chunk
    const int R = g + 1;
    const int ts = (c * R) >> 2, te = ((c + 1) * R) >> 2;
    const int q0 = g * 64;
    const size_t rowb = (size_t)b * SEQ;
    const int koff = kh * 32;

    const unsigned short* KbB = Kb + rowb * HD;
    const unsigned short* VtB = Vt + (size_t)b * HD * SEQ;
    const int vgran = ((l & 7) ^ (l >> 3)) * 8;

    auto stage = [&](int it, char* base) {
        const int j0 = it * 64;
        #pragma unroll
        for (int j = 0; j < 4; ++j) {
            int rK = w * 16 + 4 * j + (l >> 4);
            dma16(base + (w * 16 + 4 * j) * 256,
                  KbB + (size_t)(j0 + rK) * 128 + (((l & 15) ^ (rK & 7)) * 8));
            int rV = w * 32 + 8 * j + (l >> 3);
            dma16(base + 16384 + (w * 32 + 8 * j) * 128,
                  VtB + (size_t)rV * SEQ + j0 + vgran);
        }
    };

    // Q as B-operand: B[k=d][n=q], lane n=li -> q, 8 contiguous d (= row-major load)
    bf16x8 qf[2][4];
    #pragma unroll
    for (int qt = 0; qt < 2; ++qt)
        #pragma unroll
        for (int ks = 0; ks < 4; ++ks)
            qf[qt][ks] = *reinterpret_cast<const bf16x8*>(
                Qb + (rowb + q0 + qh * 32 + qt * 16 + li) * HD + ks * 32 + g2 * 8);

    f32x4 acco[2][8];        // [qt][dt]: q=li, d=dt*16+g2*4+r
    #pragma unroll
    for (int qt = 0; qt < 2; ++qt)
        #pragma unroll
        for (int dt = 0; dt < 8; ++dt) acco[qt][dt] = (f32x4){0.f, 0.f, 0.f, 0.f};
    float ls[2] = {0.f, 0.f};   // per-lane: column q=li (per qt tile)

    const int gV = ((4 * kh + g2) ^ (li & 7)) * 16;   // V read granule offset

    if (ts < te) stage(ts, smem);
    for (int it = ts; it < te; ++it) {
        char* cbuf = smem + ((it - ts) & 1) * 32768;
        char* nbuf = smem + (((it - ts) & 1) ^ 1) * 32768;
        drain_dma();
        __syncthreads();
        if (it + 1 < te) stage(it + 1, nbuf);   // overlaps compute below

        // S^T = K.Q^T : rows=key (koff+kt*16+g2*4+r), cols=q (li)
        f32x4 accs[2][2];
        #pragma unroll
        for (int qt = 0; qt < 2; ++qt)
            #pragma unroll
            for (int kt = 0; kt < 2; ++kt) accs[qt][kt] = (f32x4){0.f, 0.f, 0.f, 0.f};
        #pragma unroll
        for (int kt = 0; kt < 2; ++kt) {
            const char* kb = cbuf + (koff + kt * 16 + li) * 256;
            #pragma unroll
            for (int ks = 0; ks < 4; ++ks) {
                bf16x8 kf = *reinterpret_cast<const bf16x8*>(kb + (((4 * ks + g2) ^ (li & 7)) * 16));
                accs[0][kt] = __builtin_amdgcn_mfma_f32_16x16x32_bf16(kf, qf[0][ks], accs[0][kt], 0, 0, 0);
                accs[1][kt] = __builtin_amdgcn_mfma_f32_16x16x32_bf16(kf, qf[1][ks], accs[1][kt], 0, 0, 0);
            }
        }

        const bool masked = (it == g);
        #pragma unroll
        for (int qt = 0; qt < 2; ++qt) {
            const int prow = qh * 32 + qt * 16 + li;       // block-local q
            #pragma unroll
            for (int kt = 0; kt < 2; ++kt) {
                float p[4];
                #pragma unroll
                for (int r = 0; r < 4; ++r) {
                    float s = accs[qt][kt][r];
                    if (masked && (koff + kt * 16 + g2 * 4 + r > prow)) s = -INFINITY;
                    p[r] = __builtin_amdgcn_exp2f(s - 16.0f);
                    ls[qt] += p[r];
                }
                // P^T[q][key] : lane writes 4 contiguous keys = one b64 store
                union { u32 d[2]; uint2 v; } pw;
                pw.d[0] = pk2(p[0], p[1]); pw.d[1] = pk2(p[2], p[3]);
                int gr = (kh * 4 + kt * 2 + (g2 >> 1)) ^ (prow & 7);
                *reinterpret_cast<uint2*>(
                    smem + 65536 + prow * 128 + gr * 16 + (g2 & 1) * 8) = pw.v;
            }
        }

        // In-wave P^T write->read only (same rows/granules); lgkmcnt orders.
        bf16x8 pb[2];
        #pragma unroll
        for (int qt = 0; qt < 2; ++qt) {
            const int prow = qh * 32 + qt * 16 + li;
            pb[qt] = *reinterpret_cast<const bf16x8*>(
                smem + 65536 + prow * 128 + (((kh * 4 + g2) ^ (prow & 7)) * 16));
        }
        #pragma unroll
        for (int dt = 0; dt < 8; ++dt) {
            bf16x8 va = *reinterpret_cast<const bf16x8*>(cbuf + 16384 + (dt * 16 + li) * 128 + gV);
            acco[0][dt] = __builtin_amdgcn_mfma_f32_16x16x32_bf16(va, pb[0], acco[0][dt], 0, 0, 0);
            acco[1][dt] = __builtin_amdgcn_mfma_f32_16x16x32_bf16(va, pb[1], acco[1][dt], 0, 0, 0);
        }
    }

    // per-lane l: combine the 4 key-quads (lanes 16 apart hold same q)
    #pragma unroll
    for (int qt = 0; qt < 2; ++qt) {
        ls[qt] += __shfl_xor(ls[qt], 16);
        ls[qt] += __shfl_xor(ls[qt], 32);
    }

    // combine kh halves via LDS overlay (stage buffers dead now)
    float (*Osum)[132] = (float(*)[132])smem;        // 64 x 128 (+4 pad) f32 = [0,33792)
    float* Lsh = (float*)(smem + 33792);             // [2][64]
    __syncthreads();
    if (l < 16) {
        Lsh[kh * 64 + qh * 32 + l]      = ls[0];
        Lsh[kh * 64 + qh * 32 + 16 + l] = ls[1];
    }
    if (kh == 0) {
        #pragma unroll
        for (int qt = 0; qt < 2; ++qt)
            #pragma unroll
            for (int dt = 0; dt < 8; ++dt)
                *reinterpret_cast<f32x4*>(
                    &Osum[qh * 32 + qt * 16 + li][dt * 16 + g2 * 4]) = acco[qt][dt];
    }
    __syncthreads();
    if (kh == 1) {
        #pragma unroll
        for (int qt = 0; qt < 2; ++qt)
            #pragma unroll
            for (int dt = 0; dt < 8; ++dt) {
                f32x4* p = reinterpret_cast<f32x4*>(
                    &Osum[qh * 32 + qt * 16 + li][dt * 16 + g2 * 4]);
                f32x4 v = *p;
                #pragma unroll
                for (int j = 0; j < 4; ++j) v[j] += acco[qt][dt][j];
                *p = v;
            }
    }
    __syncthreads();

    if (t < 64)
        Lbuf[(size_t)c * 16384 + rowb + q0 + t] = Lsh[t] + Lsh[64 + t];
    #pragma unroll
    for (int k = 0; k < 8; ++k) {
        int idx = t + k * 256;
        int row = idx >> 5, col = (idx & 31) * 4;
        f32x4 o = *reinterpret_cast<const f32x4*>(&Osum[row][col]);
        size_t grow = rowb + q0 + row;
        if (c == 3) {
            *reinterpret_cast<f32x4*>(&outO[grow * HD + col]) = o;
        } else {
            union { u32 d[2]; uint2 v; } pkd;
            pkd.d[0] = pk2(o[0], o[1]); pkd.d[1] = pk2(o[2], o[3]);
            *reinterpret_cast<uint2*>(&Obf[(size_t)c * 2097152 + grow * HD + col]) = pkd.v;
        }
    }
}

// ---------------------------------------------------------------------------
// Merge: out = (Obf[0]+Obf[1]+Obf[2]+out) / (l0+l1+l2+l3)
__global__ __launch_bounds__(256)
void merge_kernel(float* __restrict__ outO, const unsigned short* __restrict__ Obf,
                  const float* __restrict__ Lbuf) {
    int tid = blockIdx.x * 256 + threadIdx.x;
    #pragma unroll
    for (int k = 0; k < 4; ++k) {
        int idx = tid + k * 131072;
        int row = idx >> 5, col = (idx & 31) * 4;
        float lsum = Lbuf[row] + Lbuf[16384 + row] + Lbuf[32768 + row] + Lbuf[49152 + row];
        float inv = 1.f / lsum;
        f32x4 o = *reinterpret_cast<const f32x4*>(&outO[(size_t)row * HD + col]);
        #pragma unroll
        for (int cc = 0; cc < 3; ++cc) {
            ushort4 uu = *reinterpret_cast<const ushort4*>(
                &Obf[(size_t)cc * 2097152 + (size_t)row * HD + col]);
            union { u32 u; float f; } a, b2, c2, d2;
            a.u = (u32)uu.x << 16; b2.u = (u32)uu.y << 16;
            c2.u = (u32)uu.z << 16; d2.u = (u32)uu.w << 16;
            o[0] += a.f; o[1] += b2.f; o[2] += c2.f; o[3] += d2.f;
        }
        #pragma unroll
        for (int j = 0; j < 4; ++j) o[j] *= inv;
        *reinterpret_cast<f32x4*>(&outO[(size_t)row * HD + col]) = o;
    }
}

// ---------------------------------------------------------------------------
extern "C" void kernel_launch(void* const* d_in, const int* in_sizes, int n_in,
                              void* d_out, int out_size, void* d_ws, size_t ws_size,
                              hipStream_t stream) {
    const float* x  = (const float*)d_in[0];
    const float* Wq = (const float*)d_in[1];
    const float* Wk = (const float*)d_in[2];
    const float* Wv = (const float*)d_in[3];
    float* out = (float*)d_out;

    char* ws = (char*)d_ws;
    unsigned short* Qb  = (unsigned short*)(ws);                        // 4 MB
    unsigned short* Kb  = (unsigned short*)(ws + ((size_t)4  << 20));   // 4 MB
    unsigned short* Vt  = (unsigned short*)(ws + ((size_t)8  << 20));   // 4 MB
    unsigned short* Wt  = (unsigned short*)(ws + ((size_t)12 << 20));   // 768 KB
    unsigned short* Obf = (unsigned short*)(ws + ((size_t)13 << 20));   // 3 x 4 MB
    float*          Lb  = (float*)(ws + ((size_t)25 << 20));            // 4 x 64 KB

    wt_kernel   <<<dim3(16, 3), dim3(256), 0, stream>>>(Wq, Wk, Wv, Wt);
    proj_kernel <<<dim3(768),   dim3(256), 0, stream>>>(x, Wt, Qb, Kb, Vt);
    attn_kernel <<<dim3(1024),  dim3(256), 0, stream>>>(Qb, Kb, Vt, out, Obf, Lb);
    merge_kernel<<<dim3(512),   dim3(256), 0, stream>>>(out, Obf, Lb);
}